// Round 14
// baseline (982.500 us; speedup 1.0000x reference)
//
#include <hip/hip_runtime.h>
#include <hip/hip_bf16.h>
#include <cstdint>
#include <cstddef>

typedef __bf16 bf16;
typedef __bf16 bf16x2 __attribute__((ext_vector_type(2)));
typedef __bf16 bf16x4 __attribute__((ext_vector_type(4)));
typedef __bf16 bf16x8 __attribute__((ext_vector_type(8)));
typedef float f32x4 __attribute__((ext_vector_type(4)));
typedef float f32x16 __attribute__((ext_vector_type(16)));

// ---------------- constants ----------------
#define EDIM 2048
#define SEQ  2048
#define BATCH 2
#define NH   32
#define NKV  8
#define HD   64
#define FF   8192
#define NTOK 4096          // BATCH*SEQ
#define QKVN 3072          // EDIM + 2*512

// async 16B global -> LDS (lane-contiguous LDS layout required)
__device__ __forceinline__ void gld_lds16(const void* gp, void* lp) {
    __builtin_amdgcn_global_load_lds(
        (__attribute__((address_space(1))) void*)(gp),
        (__attribute__((address_space(3))) void*)(lp), 16, 0, 0);
}

// ---- shared block remap: XCD chunk + 8x8 supertile (bijective when nwg%64==0,
//      gx%8==0, gy%8==0; falls back to identity otherwise) ----
__device__ __forceinline__ void remap_xcd(int& bx, int& by) {
    int gx = gridDim.x, gy = gridDim.y;
    int nwg = gx * gy;
    if (((nwg & 63) | (gx & 7) | (gy & 7)) == 0) {
        int l = bx + gx * by;
        int nl = (l & 7) * (nwg >> 3) + (l >> 3);   // XCD gets contiguous range
        int s = nl >> 6, r = nl & 63;               // 8x8 supertile of blocks
        int spr = gx >> 3;                          // supertiles per row
        bx = (s % spr) * 8 + (r & 7);
        by = (s / spr) * 8 + (r >> 3);
    }
}

// ---------------- fp32 -> bf16 convert (2-tensor + 3-tensor fused) ----------------
__global__ __launch_bounds__(256)
void cvt2_f32_bf16(const float* __restrict__ inA, bf16* __restrict__ outA, long nA4,
                   const float* __restrict__ inB, bf16* __restrict__ outB, long nB4) {
    long i = (long)blockIdx.x * blockDim.x + threadIdx.x;
    long stride = (long)gridDim.x * blockDim.x;
    for (long k = i; k < nA4; k += stride) {
        float4 v = ((const float4*)inA)[k];
        bf16x4 o; o[0]=(bf16)v.x; o[1]=(bf16)v.y; o[2]=(bf16)v.z; o[3]=(bf16)v.w;
        ((bf16x4*)outA)[k] = o;
    }
    for (long k = i; k < nB4; k += stride) {
        float4 v = ((const float4*)inB)[k];
        bf16x4 o; o[0]=(bf16)v.x; o[1]=(bf16)v.y; o[2]=(bf16)v.z; o[3]=(bf16)v.w;
        ((bf16x4*)outB)[k] = o;
    }
}

__global__ __launch_bounds__(256)
void cvt3_f32_bf16(const float* __restrict__ i0, bf16* __restrict__ o0,
                   const float* __restrict__ i1, bf16* __restrict__ o1,
                   const float* __restrict__ i2, bf16* __restrict__ o2, long n4) {
    long i = (long)blockIdx.x * blockDim.x + threadIdx.x;
    long stride = (long)gridDim.x * blockDim.x;
    for (long k = i; k < n4; k += stride) {
        float4 v = ((const float4*)i0)[k];
        bf16x4 o; o[0]=(bf16)v.x; o[1]=(bf16)v.y; o[2]=(bf16)v.z; o[3]=(bf16)v.w;
        ((bf16x4*)o0)[k] = o;
        float4 w = ((const float4*)i1)[k];
        bf16x4 p; p[0]=(bf16)w.x; p[1]=(bf16)w.y; p[2]=(bf16)w.z; p[3]=(bf16)w.w;
        ((bf16x4*)o1)[k] = p;
        float4 u = ((const float4*)i2)[k];
        bf16x4 q; q[0]=(bf16)u.x; q[1]=(bf16)u.y; q[2]=(bf16)u.z; q[3]=(bf16)u.w;
        ((bf16x4*)o2)[k] = q;
    }
}

// ---------------- RMSNorm: fp32 row -> bf16 row ----------------
__global__ __launch_bounds__(256)
void rmsnorm_bf16(const float* __restrict__ x, const float* __restrict__ w,
                  bf16* __restrict__ out) {
    __shared__ float red[4];
    const int row = blockIdx.x;
    const long base = (long)row * EDIM;
    const int t = threadIdx.x;
    float4 v0 = *(const float4*)(x + base + t * 4);
    float4 v1 = *(const float4*)(x + base + 1024 + t * 4);
    float ss = v0.x*v0.x + v0.y*v0.y + v0.z*v0.z + v0.w*v0.w
             + v1.x*v1.x + v1.y*v1.y + v1.z*v1.z + v1.w*v1.w;
    #pragma unroll
    for (int off = 1; off < 64; off <<= 1) ss += __shfl_xor(ss, off, 64);
    if ((t & 63) == 0) red[t >> 6] = ss;
    __syncthreads();
    float tot = red[0] + red[1] + red[2] + red[3];
    float inv = rsqrtf(tot * (1.0f / EDIM) + 1e-5f);
    float4 w0 = *(const float4*)(w + t * 4);
    float4 w1 = *(const float4*)(w + 1024 + t * 4);
    bf16x4 o0, o1;
    o0[0] = (bf16)(v0.x * inv * w0.x); o0[1] = (bf16)(v0.y * inv * w0.y);
    o0[2] = (bf16)(v0.z * inv * w0.z); o0[3] = (bf16)(v0.w * inv * w0.w);
    o1[0] = (bf16)(v1.x * inv * w1.x); o1[1] = (bf16)(v1.y * inv * w1.y);
    o1[2] = (bf16)(v1.z * inv * w1.z); o1[3] = (bf16)(v1.w * inv * w1.w);
    *(bf16x4*)(out + base + t * 4) = o0;
    *(bf16x4*)(out + base + 1024 + t * 4) = o1;
}

// ---------------- NT GEMM: C[M,N] = A[M,K] * B[N,K]^T ----------------
// 128x128 tile, BK=64 (two 32-wide halves per barrier pair -> 32 MFMA/barrier).
// LDS rows are 128B so chunk placement is XOR-swizzled (rule #21: linear LDS
// dest for gld_lds, permuted GLOBAL source chunk, same involution on ds_read):
// slot(r, j) holds global chunk j^(r&7) -> conflict-free reads (measured 0).
// EPI: 0 = f32 store, 1 = bf16 store, 2 = f32 store + f32 residual add
template<int EPI>
__global__ __launch_bounds__(256, 4)
void gemm_nt(const bf16* __restrict__ A, const bf16* __restrict__ B,
             void* __restrict__ Cv, const float* __restrict__ res,
             int M, int N, int K) {
    __shared__ bf16 As[128 * 64];
    __shared__ bf16 Bs[128 * 64];
    const int tid = threadIdx.x;
    const int lane = tid & 63;
    const int wave = tid >> 6;
    const int wm = (wave >> 1) * 64;
    const int wn = (wave & 1) * 64;

    int bx = blockIdx.x, by = blockIdx.y;
    remap_xcd(bx, by);
    const int bm = by * 128;
    const int bn = bx * 128;
    const int lrow = lane & 15;
    const int g = lane >> 4;

    f32x4 acc[4][4] = {};

    for (int k0 = 0; k0 < K; k0 += 64) {
        __syncthreads();
        #pragma unroll
        for (int t = 0; t < 4; ++t) {
            int c = tid + t * 256;               // 1024 chunks of 16B per tile
            int r = c >> 3;
            int kc = ((c & 7) ^ (r & 7)) * 8;    // XOR-swizzled source chunk
            gld_lds16(A + (long)(bm + r) * K + k0 + kc, As + c * 8);
            gld_lds16(B + (long)(bn + r) * K + k0 + kc, Bs + c * 8);
        }
        __syncthreads();
        #pragma unroll
        for (int hf = 0; hf < 2; ++hf) {
            bf16x8 af[4], bfr[4];
            #pragma unroll
            for (int t = 0; t < 4; ++t) {
                int ra = wm + t * 16 + lrow;
                int rb = wn + t * 16 + lrow;
                af[t]  = *(const bf16x8*)(As + ra * 64 + ((((hf << 2) + g) ^ (ra & 7)) << 3));
                bfr[t] = *(const bf16x8*)(Bs + rb * 64 + ((((hf << 2) + g) ^ (rb & 7)) << 3));
            }
            #pragma unroll
            for (int i = 0; i < 4; ++i)
                #pragma unroll
                for (int j = 0; j < 4; ++j)
                    acc[i][j] = __builtin_amdgcn_mfma_f32_16x16x32_bf16(af[i], bfr[j], acc[i][j], 0, 0, 0);
        }
    }

    const int row0 = bm + wm + (lane >> 4) * 4;
    const int col0 = bn + wn + (lane & 15);
    #pragma unroll
    for (int i = 0; i < 4; ++i) {
        #pragma unroll
        for (int j = 0; j < 4; ++j) {
            int col = col0 + j * 16;
            #pragma unroll
            for (int r = 0; r < 4; ++r) {
                long idx = (long)(row0 + i * 16 + r) * N + col;
                float v = acc[i][j][r];
                if (EPI == 0) {
                    ((float*)Cv)[idx] = v;
                } else if (EPI == 1) {
                    ((bf16*)Cv)[idx] = (bf16)v;
                } else {
                    ((float*)Cv)[idx] = v + res[idx];
                }
            }
        }
    }
}

// ---------------- fused SwiGLU GEMM: C = silu(A*B1^T) * (A*B3^T), bf16 out ----------------
// Same structure, BK=64: A staged once, B1+B3 alongside (48 KB LDS, 2 blocks/CU),
// 64 MFMA per barrier pair; SwiGLU combined in-register (no u round trip).
__global__ __launch_bounds__(256, 2)
void gemm_ff(const bf16* __restrict__ A, const bf16* __restrict__ B1,
             const bf16* __restrict__ B3, bf16* __restrict__ C,
             int M, int N, int K) {
    __shared__ bf16 As[128 * 64];
    __shared__ bf16 B1s[128 * 64];
    __shared__ bf16 B3s[128 * 64];
    const int tid = threadIdx.x;
    const int lane = tid & 63;
    const int wave = tid >> 6;
    const int wm = (wave >> 1) * 64;
    const int wn = (wave & 1) * 64;

    int bx = blockIdx.x, by = blockIdx.y;
    remap_xcd(bx, by);
    const int bm = by * 128;
    const int bn = bx * 128;
    const int lrow = lane & 15;
    const int g = lane >> 4;

    f32x4 accu[4][4] = {};
    f32x4 accv[4][4] = {};

    for (int k0 = 0; k0 < K; k0 += 64) {
        __syncthreads();
        #pragma unroll
        for (int t = 0; t < 4; ++t) {
            int c = tid + t * 256;               // 1024 chunks of 16B per tile
            int r = c >> 3;
            int kc = ((c & 7) ^ (r & 7)) * 8;    // XOR-swizzled source chunk
            gld_lds16(A  + (long)(bm + r) * K + k0 + kc, As  + c * 8);
            gld_lds16(B1 + (long)(bn + r) * K + k0 + kc, B1s + c * 8);
            gld_lds16(B3 + (long)(bn + r) * K + k0 + kc, B3s + c * 8);
        }
        __syncthreads();
        #pragma unroll
        for (int hf = 0; hf < 2; ++hf) {
            bf16x8 af[4], b1f[4], b3f[4];
            #pragma unroll
            for (int t = 0; t < 4; ++t) {
                int ra = wm + t * 16 + lrow;
                int rb = wn + t * 16 + lrow;
                int ca = (((hf << 2) + g) ^ (ra & 7)) << 3;
                int cb = (((hf << 2) + g) ^ (rb & 7)) << 3;
                af[t]  = *(const bf16x8*)(As  + ra * 64 + ca);
                b1f[t] = *(const bf16x8*)(B1s + rb * 64 + cb);
                b3f[t] = *(const bf16x8*)(B3s + rb * 64 + cb);
            }
            #pragma unroll
            for (int i = 0; i < 4; ++i)
                #pragma unroll
                for (int j = 0; j < 4; ++j) {
                    accu[i][j] = __builtin_amdgcn_mfma_f32_16x16x32_bf16(af[i], b1f[j], accu[i][j], 0, 0, 0);
                    accv[i][j] = __builtin_amdgcn_mfma_f32_16x16x32_bf16(af[i], b3f[j], accv[i][j], 0, 0, 0);
                }
        }
    }

    const int row0 = bm + wm + (lane >> 4) * 4;
    const int col0 = bn + wn + (lane & 15);
    #pragma unroll
    for (int i = 0; i < 4; ++i) {
        #pragma unroll
        for (int j = 0; j < 4; ++j) {
            int col = col0 + j * 16;
            #pragma unroll
            for (int r = 0; r < 4; ++r) {
                long idx = (long)(row0 + i * 16 + r) * N + col;
                float u = accu[i][j][r];
                float v = accv[i][j][r];
                float sl = u / (1.0f + __expf(-u));
                C[idx] = (bf16)(sl * v);
            }
        }
    }
}

// ---------------- RoPE prep: qkv bf16 [4096,3072] -> Q [B,H,S,64], K [B,KH,S,64] ----------------
// NOTE: Q is prescaled by 1/sqrt(HD) = 0.125 here (exact power-of-2 in bf16),
// so attn_fwd uses raw QK^T scores.
__global__ __launch_bounds__(256)
void rope_prep(const bf16* __restrict__ qkv, const float* __restrict__ fr,
               bf16* __restrict__ Qo, bf16* __restrict__ Ko) {
    const int row = blockIdx.x;            // b*SEQ + s
    const int b = row >> 11, s = row & 2047;
    const int t = threadIdx.x;
    const long rbase = (long)row * QKVN;
    #pragma unroll
    for (int i = 0; i < 4; ++i) {          // 1024 q pairs
        int p = t + i * 256;
        int hh = p >> 5, d = p & 31;
        bf16x2 xv = *(const bf16x2*)(qkv + rbase + hh * 64 + 2 * d);
        float x0 = (float)xv[0], x1 = (float)xv[1];
        float2 cs = *(const float2*)(fr + (long)(s * 32 + d) * 2);
        bf16x2 o;
        o[0] = (bf16)((x0 * cs.x - x1 * cs.y) * 0.125f);
        o[1] = (bf16)((x1 * cs.x + x0 * cs.y) * 0.125f);
        *(bf16x2*)(Qo + ((long)(b * NH + hh) * SEQ + s) * HD + 2 * d) = o;
    }
    {                                       // 256 k pairs
        int kh = t >> 5, d = t & 31;
        bf16x2 xv = *(const bf16x2*)(qkv + rbase + EDIM + kh * 64 + 2 * d);
        float x0 = (float)xv[0], x1 = (float)xv[1];
        float2 cs = *(const float2*)(fr + (long)(s * 32 + d) * 2);
        bf16x2 o;
        o[0] = (bf16)(x0 * cs.x - x1 * cs.y);
        o[1] = (bf16)(x1 * cs.x + x0 * cs.y);
        *(bf16x2*)(Ko + ((long)(b * NKV + kh) * SEQ + s) * HD + 2 * d) = o;
    }
}

// ---------------- V prep: transpose into [B,KH,S/64,hd=64,kk=64] bf16 tiles ----------------
__global__ __launch_bounds__(256)
void v_prep(const bf16* __restrict__ qkv, bf16* __restrict__ Vt) {
    __shared__ bf16 tile[64 * 72];          // +8 pad to break transpose conflicts
    const int blk = blockIdx.x;             // b*256 + kvh*32 + st
    const int b = blk >> 8;
    const int kvh = (blk >> 5) & 7;
    const int st = blk & 31;
    const int t = threadIdx.x;
    #pragma unroll
    for (int i = 0; i < 2; ++i) {
        int c = t + i * 256;                // 512 chunks
        int kk = c >> 3, hdo = (c & 7) * 8;
        bf16x8 v = *(const bf16x8*)(qkv + (long)(b * SEQ + st * 64 + kk) * QKVN + 2560 + kvh * 64 + hdo);
        *(bf16x8*)(tile + kk * 72 + hdo) = v;
    }
    __syncthreads();
    const long obase = ((long)(b * NKV + kvh) * 32 + st) * 4096;
    #pragma unroll
    for (int i = 0; i < 2; ++i) {
        int c = t + i * 256;
        int hd = c >> 3, ko = (c & 7) * 8;
        bf16x8 v;
        #pragma unroll
        for (int j = 0; j < 8; ++j) v[j] = tile[(ko + j) * 72 + hd];
        *(bf16x8*)(Vt + obase + hd * 64 + ko) = v;
    }
}

// ---------------- flash attention (causal, GQA 4:1), swapped-QK^T ----------------
// 4 waves/block, each wave owns 32 q-rows independently (no block barriers).
// (256,3): attn's live set needs the ~170-reg budget; forcing 4 blocks/CU
// (128-reg cap) spills and regresses ~2x (R11).
// LPT scheduling: qt axis is FLIPPED (qt = gy-1-blockIdx.y) so the heaviest
// causal tiles (large qt, ~2x average work) launch first and the light tiles
// backfill -- removes the straggler wave of heavy blocks at 1024 blocks vs
// 768 co-resident slots.
__global__ __launch_bounds__(256, 3)
void attn_fwd(const bf16* __restrict__ Q, const bf16* __restrict__ K,
              const bf16* __restrict__ Vt, bf16* __restrict__ Out) {
    __shared__ bf16 Ps[4][32][40];           // per-wave P, 40-elem stride (80B = 5x16B)
    const int tid = threadIdx.x, lane = tid & 63, w = tid >> 6;
    const int bh = blockIdx.x;               // batch*head (fast grid dim for balance)
    const int qt = gridDim.y - 1 - blockIdx.y;   // 128-row q tile, LPT-flipped
    const int b = bh >> 5, h = bh & 31;
    const int kvh = h >> 2;
    const int ql = lane & 31;                // q-row owned by this lane
    const int hh = lane >> 5;                // lane half
    const int sw = (ql ^ (ql >> 3)) & 3;     // LDS 16B-block swizzle key
    const int q0 = qt * 128 + w * 32;        // wave's q base within seq
    const int qmax = q0 + 31;
    const long qbase  = ((long)(b * NH + h) * SEQ + q0) * HD;
    const long kvbase = ((long)(b * NKV + kvh) * SEQ) * HD;
    bf16* Pw = &Ps[w][0][0];

    bf16x8 qa[4];
    #pragma unroll
    for (int ds = 0; ds < 4; ++ds)
        qa[ds] = *(const bf16x8*)(Q + qbase + (long)ql * HD + ds * 16 + hh * 8);

    f32x16 oacc[2] = {};                     // O^T accumulators (2 d-tiles of 32)
    float mi = -1e30f, li = 0.f;

    const int nt64 = qt * 2 + 1 + (w >> 1);
    for (int kt = 0; kt < nt64; ++kt) {
        const bf16* Kt  = K  + kvbase + (long)kt * (64 * HD);
        const bf16* Vtt = Vt + kvbase + (long)kt * 4096;
        bf16x8 ka[2][4], va[2][2][2];
        #pragma unroll
        for (int h2 = 0; h2 < 2; ++h2)
            #pragma unroll
            for (int ds = 0; ds < 4; ++ds)
                ka[h2][ds] = *(const bf16x8*)(Kt + (h2 * 32 + ql) * HD + ds * 16 + hh * 8);
        #pragma unroll
        for (int h2 = 0; h2 < 2; ++h2)
            #pragma unroll
            for (int t = 0; t < 2; ++t)
                #pragma unroll
                for (int c = 0; c < 2; ++c)
                    va[h2][t][c] = *(const bf16x8*)(Vtt + (t * 32 + ql) * 64 + h2 * 32 + c * 16 + hh * 8);
        const bool lastt = (kt == nt64 - 1);
        #pragma unroll
        for (int h2 = 0; h2 < 2; ++h2) {
            if (h2 == 1 && kt * 64 + 32 > qmax) break;   // wave-uniform skip
            f32x16 s = {};
            #pragma unroll
            for (int ds = 0; ds < 4; ++ds)
                s = __builtin_amdgcn_mfma_f32_32x32x16_bf16(ka[h2][ds], qa[ds], s, 0, 0, 0);
            if (lastt) {
                #pragma unroll
                for (int r = 0; r < 16; ++r) {
                    int kk = kt * 64 + h2 * 32 + (r & 3) + 8 * (r >> 2) + 4 * hh;
                    if (kk > q0 + ql) s[r] = -1e30f;
                }
            }
            float tmax = s[0];
            #pragma unroll
            for (int r = 1; r < 16; ++r) tmax = fmaxf(tmax, s[r]);
            tmax = fmaxf(tmax, __shfl_xor(tmax, 32, 64));
            if (!__all(tmax <= mi)) {
                float mnew = fmaxf(mi, tmax);
                float alpha = __expf(mi - mnew);
                li *= alpha;
                #pragma unroll
                for (int r = 0; r < 16; ++r) { oacc[0][r] *= alpha; oacc[1][r] *= alpha; }
                mi = mnew;
            }
            float psum = 0.f;
            #pragma unroll
            for (int g2 = 0; g2 < 4; ++g2) {
                bf16x4 pw;
                #pragma unroll
                for (int j = 0; j < 4; ++j) {
                    float p = __expf(s[g2 * 4 + j] - mi);
                    psum += p;
                    pw[j] = (bf16)p;
                }
                *(bf16x4*)(Pw + ql * 40 + ((g2 ^ sw) << 3) + 4 * hh) = pw;
            }
            psum += __shfl_xor(psum, 32, 64);
            li += psum;
            bf16x8 p0 = *(const bf16x8*)(Pw + ql * 40 + ((hh ^ sw) << 3));
            bf16x8 p1 = *(const bf16x8*)(Pw + ql * 40 + (((2 + hh) ^ sw) << 3));
            #pragma unroll
            for (int t = 0; t < 2; ++t) {
                oacc[t] = __builtin_amdgcn_mfma_f32_32x32x16_bf16(va[h2][t][0], p0, oacc[t], 0, 0, 0);
                oacc[t] = __builtin_amdgcn_mfma_f32_32x32x16_bf16(va[h2][t][1], p1, oacc[t], 0, 0, 0);
            }
        }
    }

    float inv = 1.0f / li;
    const long obase = ((long)b * SEQ + q0 + ql) * EDIM + h * 64;
    #pragma unroll
    for (int t = 0; t < 2; ++t)
        #pragma unroll
        for (int rg = 0; rg < 4; ++rg) {
            bf16x4 o4;
            #pragma unroll
            for (int j = 0; j < 4; ++j) o4[j] = (bf16)(oacc[t][rg * 4 + j] * inv);
            *(bf16x4*)(Out + obase + t * 32 + rg * 8 + hh * 4) = o4;
        }
}

// ---------------- launcher ----------------
extern "C" void kernel_launch(void* const* d_in, const int* in_sizes, int n_in,
                              void* d_out, int out_size, void* d_ws, size_t ws_size,
                              hipStream_t stream) {
    const float* x    = (const float*)d_in[0];
    // d_in[1] = attention_mask (always causal tril; handled analytically)
    const float* fr   = (const float*)d_in[2];
    const float* wqkv = (const float*)d_in[3];
    const float* wo   = (const float*)d_in[4];
    const float* w1   = (const float*)d_in[5];
    const float* w2   = (const float*)d_in[6];
    const float* w3   = (const float*)d_in[7];
    const float* anw  = (const float*)d_in[8];
    const float* fnw  = (const float*)d_in[9];
    float* out = (float*)d_out;

    // ---- workspace budget (aliased layout), ~252 MiB ----
    const size_t SZ_WQKV = (size_t)QKVN * EDIM;     // 6291456
    const size_t SZ_WO   = (size_t)EDIM * EDIM;     // 4194304
    const size_t SZ_WFF  = (size_t)FF * EDIM;       // 16777216
    const size_t B_WQKV  = SZ_WQKV * 2;             // 12.6 MB
    const size_t B_WO    = SZ_WO * 2;               //  8.4 MB
    const size_t B_WFF   = SZ_WFF * 2;              // 33.6 MB
    const size_t B_HATTN = (size_t)NTOK * EDIM * 2; // 16.8 MB
    const size_t B_QKV   = (size_t)NTOK * QKVN * 2; // 25.2 MB
    const size_t B_SCR   = (size_t)NTOK * EDIM * 4; // 33.6 MB (h2 fp32; aliases Q/K/Vt)
    const size_t B_FF1   = (size_t)NTOK * FF * 2;   // 67.1 MB
    const size_t NEED = B_WQKV + B_WO + 3 * B_WFF + B_HATTN + B_QKV + B_SCR + B_FF1;
    if (ws_size < NEED) return;   // diagnostic: clean absmax-fail instead of GPU fault

    char* ws = (char*)d_ws;
    size_t off = 0;
    auto alloc = [&](size_t bytes) -> void* {
        void* p = ws + off;
        off += (bytes + 255) & ~(size_t)255;
        return p;
    };
    bf16* wqkv_b = (bf16*)alloc(B_WQKV);
    bf16* wo_b   = (bf16*)alloc(B_WO);
    bf16* w1_b   = (bf16*)alloc(B_WFF);
    bf16* w3_b   = (bf16*)alloc(B_WFF);
    bf16* w2_b   = (bf16*)alloc(B_WFF);
    bf16* h_attn = (bf16*)alloc(B_HATTN);           // h, then attn_out
    bf16* qkv_g  = (bf16*)alloc(B_QKV);             // qkv, then g
    char* scr    = (char*)alloc(B_SCR);             // Q/K/Vt region, then h2
    bf16* Qb  = (bf16*)scr;                                         // 16.8 MB
    bf16* Kb  = (bf16*)(scr + (size_t)BATCH * NH * SEQ * HD * 2);   //  4.2 MB
    bf16* Vtb = (bf16*)(scr + (size_t)BATCH * (NH + NKV) * SEQ * HD * 2); // 4.2 MB
    float* h2 = (float*)scr;                        // aliases Q/K/Vt (dead by then)
    bf16* ff1 = (bf16*)alloc(B_FF1);                // SwiGLU activation (single write)
    bf16* g_b = qkv_g;                              // reuse (qkv dead after preps)

    // 1. weights -> bf16 (2 fused launches, 2048-block grids for full BW occupancy)
    cvt3_f32_bf16<<<2048, 256, 0, stream>>>(w1, w1_b, w3, w3_b, w2, w2_b,
                                            (long)(SZ_WFF / 4));
    cvt2_f32_bf16<<<2048, 256, 0, stream>>>(wqkv, wqkv_b, (long)(SZ_WQKV / 4),
                                            wo, wo_b, (long)(SZ_WO / 4));
    // 2. h = rmsnorm(x) * attn_norm_w  (bf16)
    rmsnorm_bf16<<<NTOK, 256, 0, stream>>>(x, anw, h_attn);
    // 3. qkv = h @ w_qkv^T  (bf16 out)
    gemm_nt<1><<<dim3(QKVN / 128, NTOK / 128), 256, 0, stream>>>(
        h_attn, wqkv_b, qkv_g, nullptr, NTOK, QKVN, EDIM);
    // 4. RoPE + layout prep (Q prescaled by 0.125)
    rope_prep<<<NTOK, 256, 0, stream>>>(qkv_g, fr, Qb, Kb);
    v_prep<<<BATCH * NKV * (SEQ / 64), 256, 0, stream>>>(qkv_g, Vtb);
    // 5. attention -> attn_out (bf16, [4096,2048]); grid (bh, qt), LPT qt-flip
    attn_fwd<<<dim3(BATCH * NH, SEQ / 128), 256, 0, stream>>>(Qb, Kb, Vtb, h_attn);
    // 6. h2 = x + attn_out @ w_o^T  (fp32; h2 aliases dead Q/K/Vt)
    gemm_nt<2><<<dim3(EDIM / 128, NTOK / 128), 256, 0, stream>>>(
        h_attn, wo_b, h2, x, NTOK, EDIM, EDIM);
    // 7. g = rmsnorm(h2) * ff_norm_w (bf16)
    rmsnorm_bf16<<<NTOK, 256, 0, stream>>>(h2, fnw, g_b);
    // 8. act = silu(g @ w1^T) * (g @ w3^T)  -- ONE fused kernel, in-register SwiGLU
    gemm_ff<<<dim3(FF / 128, NTOK / 128), 256, 0, stream>>>(
        g_b, w1_b, w3_b, ff1, NTOK, FF, EDIM);
    // 9. out = h2 + act @ w2^T  (fp32)
    gemm_nt<2><<<dim3(EDIM / 128, NTOK / 128), 256, 0, stream>>>(
        ff1, w2_b, out, h2, NTOK, EDIM, FF);
    (void)in_sizes; (void)n_in; (void)out_size; (void)ws_size;
}

// Round 15
// 951.423 us; speedup vs baseline: 1.0327x; 1.0327x over previous
//
#include <hip/hip_runtime.h>
#include <hip/hip_bf16.h>
#include <cstdint>
#include <cstddef>

typedef __bf16 bf16;
typedef __bf16 bf16x2 __attribute__((ext_vector_type(2)));
typedef __bf16 bf16x4 __attribute__((ext_vector_type(4)));
typedef __bf16 bf16x8 __attribute__((ext_vector_type(8)));
typedef float f32x4 __attribute__((ext_vector_type(4)));
typedef float f32x16 __attribute__((ext_vector_type(16)));

// ---------------- constants ----------------
#define EDIM 2048
#define SEQ  2048
#define BATCH 2
#define NH   32
#define NKV  8
#define HD   64
#define FF   8192
#define NTOK 4096          // BATCH*SEQ
#define QKVN 3072          // EDIM + 2*512

// async 16B global -> LDS (lane-contiguous LDS layout required)
__device__ __forceinline__ void gld_lds16(const void* gp, void* lp) {
    __builtin_amdgcn_global_load_lds(
        (__attribute__((address_space(1))) void*)(gp),
        (__attribute__((address_space(3))) void*)(lp), 16, 0, 0);
}

// ---- shared block remap: XCD chunk + 8x8 supertile (bijective when nwg%64==0,
//      gx%8==0, gy%8==0; falls back to identity otherwise) ----
__device__ __forceinline__ void remap_xcd(int& bx, int& by) {
    int gx = gridDim.x, gy = gridDim.y;
    int nwg = gx * gy;
    if (((nwg & 63) | (gx & 7) | (gy & 7)) == 0) {
        int l = bx + gx * by;
        int nl = (l & 7) * (nwg >> 3) + (l >> 3);   // XCD gets contiguous range
        int s = nl >> 6, r = nl & 63;               // 8x8 supertile of blocks
        int spr = gx >> 3;                          // supertiles per row
        bx = (s % spr) * 8 + (r & 7);
        by = (s / spr) * 8 + (r >> 3);
    }
}

// ---------------- fp32 -> bf16 convert (2-tensor + 3-tensor fused) ----------------
__global__ __launch_bounds__(256)
void cvt2_f32_bf16(const float* __restrict__ inA, bf16* __restrict__ outA, long nA4,
                   const float* __restrict__ inB, bf16* __restrict__ outB, long nB4) {
    long i = (long)blockIdx.x * blockDim.x + threadIdx.x;
    long stride = (long)gridDim.x * blockDim.x;
    for (long k = i; k < nA4; k += stride) {
        float4 v = ((const float4*)inA)[k];
        bf16x4 o; o[0]=(bf16)v.x; o[1]=(bf16)v.y; o[2]=(bf16)v.z; o[3]=(bf16)v.w;
        ((bf16x4*)outA)[k] = o;
    }
    for (long k = i; k < nB4; k += stride) {
        float4 v = ((const float4*)inB)[k];
        bf16x4 o; o[0]=(bf16)v.x; o[1]=(bf16)v.y; o[2]=(bf16)v.z; o[3]=(bf16)v.w;
        ((bf16x4*)outB)[k] = o;
    }
}

__global__ __launch_bounds__(256)
void cvt3_f32_bf16(const float* __restrict__ i0, bf16* __restrict__ o0,
                   const float* __restrict__ i1, bf16* __restrict__ o1,
                   const float* __restrict__ i2, bf16* __restrict__ o2, long n4) {
    long i = (long)blockIdx.x * blockDim.x + threadIdx.x;
    long stride = (long)gridDim.x * blockDim.x;
    for (long k = i; k < n4; k += stride) {
        float4 v = ((const float4*)i0)[k];
        bf16x4 o; o[0]=(bf16)v.x; o[1]=(bf16)v.y; o[2]=(bf16)v.z; o[3]=(bf16)v.w;
        ((bf16x4*)o0)[k] = o;
        float4 w = ((const float4*)i1)[k];
        bf16x4 p; p[0]=(bf16)w.x; p[1]=(bf16)w.y; p[2]=(bf16)w.z; p[3]=(bf16)w.w;
        ((bf16x4*)o1)[k] = p;
        float4 u = ((const float4*)i2)[k];
        bf16x4 q; q[0]=(bf16)u.x; q[1]=(bf16)u.y; q[2]=(bf16)u.z; q[3]=(bf16)u.w;
        ((bf16x4*)o2)[k] = q;
    }
}

// ---------------- RMSNorm: fp32 row -> bf16 row ----------------
__global__ __launch_bounds__(256)
void rmsnorm_bf16(const float* __restrict__ x, const float* __restrict__ w,
                  bf16* __restrict__ out) {
    __shared__ float red[4];
    const int row = blockIdx.x;
    const long base = (long)row * EDIM;
    const int t = threadIdx.x;
    float4 v0 = *(const float4*)(x + base + t * 4);
    float4 v1 = *(const float4*)(x + base + 1024 + t * 4);
    float ss = v0.x*v0.x + v0.y*v0.y + v0.z*v0.z + v0.w*v0.w
             + v1.x*v1.x + v1.y*v1.y + v1.z*v1.z + v1.w*v1.w;
    #pragma unroll
    for (int off = 1; off < 64; off <<= 1) ss += __shfl_xor(ss, off, 64);
    if ((t & 63) == 0) red[t >> 6] = ss;
    __syncthreads();
    float tot = red[0] + red[1] + red[2] + red[3];
    float inv = rsqrtf(tot * (1.0f / EDIM) + 1e-5f);
    float4 w0 = *(const float4*)(w + t * 4);
    float4 w1 = *(const float4*)(w + 1024 + t * 4);
    bf16x4 o0, o1;
    o0[0] = (bf16)(v0.x * inv * w0.x); o0[1] = (bf16)(v0.y * inv * w0.y);
    o0[2] = (bf16)(v0.z * inv * w0.z); o0[3] = (bf16)(v0.w * inv * w0.w);
    o1[0] = (bf16)(v1.x * inv * w1.x); o1[1] = (bf16)(v1.y * inv * w1.y);
    o1[2] = (bf16)(v1.z * inv * w1.z); o1[3] = (bf16)(v1.w * inv * w1.w);
    *(bf16x4*)(out + base + t * 4) = o0;
    *(bf16x4*)(out + base + 1024 + t * 4) = o1;
}

// ---------------- NT GEMM: C[M,N] = A[M,K] * B[N,K]^T ----------------
// 128x128 tile, BK=64 (two 32-wide halves per barrier pair -> 32 MFMA/barrier).
// LDS rows are 128B so chunk placement is XOR-swizzled (rule #21: linear LDS
// dest for gld_lds, permuted GLOBAL source chunk, same involution on ds_read):
// slot(r, j) holds global chunk j^(r&7) -> conflict-free reads (measured 0).
// EPI: 0 = f32 store, 1 = bf16 store, 2 = f32 store + f32 residual add
template<int EPI>
__global__ __launch_bounds__(256, 4)
void gemm_nt(const bf16* __restrict__ A, const bf16* __restrict__ B,
             void* __restrict__ Cv, const float* __restrict__ res,
             int M, int N, int K) {
    __shared__ bf16 As[128 * 64];
    __shared__ bf16 Bs[128 * 64];
    const int tid = threadIdx.x;
    const int lane = tid & 63;
    const int wave = tid >> 6;
    const int wm = (wave >> 1) * 64;
    const int wn = (wave & 1) * 64;

    int bx = blockIdx.x, by = blockIdx.y;
    remap_xcd(bx, by);
    const int bm = by * 128;
    const int bn = bx * 128;
    const int lrow = lane & 15;
    const int g = lane >> 4;

    f32x4 acc[4][4] = {};

    for (int k0 = 0; k0 < K; k0 += 64) {
        __syncthreads();
        #pragma unroll
        for (int t = 0; t < 4; ++t) {
            int c = tid + t * 256;               // 1024 chunks of 16B per tile
            int r = c >> 3;
            int kc = ((c & 7) ^ (r & 7)) * 8;    // XOR-swizzled source chunk
            gld_lds16(A + (long)(bm + r) * K + k0 + kc, As + c * 8);
            gld_lds16(B + (long)(bn + r) * K + k0 + kc, Bs + c * 8);
        }
        __syncthreads();
        #pragma unroll
        for (int hf = 0; hf < 2; ++hf) {
            bf16x8 af[4], bfr[4];
            #pragma unroll
            for (int t = 0; t < 4; ++t) {
                int ra = wm + t * 16 + lrow;
                int rb = wn + t * 16 + lrow;
                af[t]  = *(const bf16x8*)(As + ra * 64 + ((((hf << 2) + g) ^ (ra & 7)) << 3));
                bfr[t] = *(const bf16x8*)(Bs + rb * 64 + ((((hf << 2) + g) ^ (rb & 7)) << 3));
            }
            #pragma unroll
            for (int i = 0; i < 4; ++i)
                #pragma unroll
                for (int j = 0; j < 4; ++j)
                    acc[i][j] = __builtin_amdgcn_mfma_f32_16x16x32_bf16(af[i], bfr[j], acc[i][j], 0, 0, 0);
        }
    }

    const int row0 = bm + wm + (lane >> 4) * 4;
    const int col0 = bn + wn + (lane & 15);
    #pragma unroll
    for (int i = 0; i < 4; ++i) {
        #pragma unroll
        for (int j = 0; j < 4; ++j) {
            int col = col0 + j * 16;
            #pragma unroll
            for (int r = 0; r < 4; ++r) {
                long idx = (long)(row0 + i * 16 + r) * N + col;
                float v = acc[i][j][r];
                if (EPI == 0) {
                    ((float*)Cv)[idx] = v;
                } else if (EPI == 1) {
                    ((bf16*)Cv)[idx] = (bf16)v;
                } else {
                    ((float*)Cv)[idx] = v + res[idx];
                }
            }
        }
    }
}

// ---------------- fused SwiGLU GEMM: C = silu(A*B1^T) * (A*B3^T), bf16 out ----------------
// Same structure, BK=64: A staged once, B1+B3 alongside (48 KB LDS, 2 blocks/CU),
// 64 MFMA per barrier pair; SwiGLU combined in-register (no u round trip).
__global__ __launch_bounds__(256, 2)
void gemm_ff(const bf16* __restrict__ A, const bf16* __restrict__ B1,
             const bf16* __restrict__ B3, bf16* __restrict__ C,
             int M, int N, int K) {
    __shared__ bf16 As[128 * 64];
    __shared__ bf16 B1s[128 * 64];
    __shared__ bf16 B3s[128 * 64];
    const int tid = threadIdx.x;
    const int lane = tid & 63;
    const int wave = tid >> 6;
    const int wm = (wave >> 1) * 64;
    const int wn = (wave & 1) * 64;

    int bx = blockIdx.x, by = blockIdx.y;
    remap_xcd(bx, by);
    const int bm = by * 128;
    const int bn = bx * 128;
    const int lrow = lane & 15;
    const int g = lane >> 4;

    f32x4 accu[4][4] = {};
    f32x4 accv[4][4] = {};

    for (int k0 = 0; k0 < K; k0 += 64) {
        __syncthreads();
        #pragma unroll
        for (int t = 0; t < 4; ++t) {
            int c = tid + t * 256;               // 1024 chunks of 16B per tile
            int r = c >> 3;
            int kc = ((c & 7) ^ (r & 7)) * 8;    // XOR-swizzled source chunk
            gld_lds16(A  + (long)(bm + r) * K + k0 + kc, As  + c * 8);
            gld_lds16(B1 + (long)(bn + r) * K + k0 + kc, B1s + c * 8);
            gld_lds16(B3 + (long)(bn + r) * K + k0 + kc, B3s + c * 8);
        }
        __syncthreads();
        #pragma unroll
        for (int hf = 0; hf < 2; ++hf) {
            bf16x8 af[4], b1f[4], b3f[4];
            #pragma unroll
            for (int t = 0; t < 4; ++t) {
                int ra = wm + t * 16 + lrow;
                int rb = wn + t * 16 + lrow;
                int ca = (((hf << 2) + g) ^ (ra & 7)) << 3;
                int cb = (((hf << 2) + g) ^ (rb & 7)) << 3;
                af[t]  = *(const bf16x8*)(As  + ra * 64 + ca);
                b1f[t] = *(const bf16x8*)(B1s + rb * 64 + cb);
                b3f[t] = *(const bf16x8*)(B3s + rb * 64 + cb);
            }
            #pragma unroll
            for (int i = 0; i < 4; ++i)
                #pragma unroll
                for (int j = 0; j < 4; ++j) {
                    accu[i][j] = __builtin_amdgcn_mfma_f32_16x16x32_bf16(af[i], b1f[j], accu[i][j], 0, 0, 0);
                    accv[i][j] = __builtin_amdgcn_mfma_f32_16x16x32_bf16(af[i], b3f[j], accv[i][j], 0, 0, 0);
                }
        }
    }

    const int row0 = bm + wm + (lane >> 4) * 4;
    const int col0 = bn + wn + (lane & 15);
    #pragma unroll
    for (int i = 0; i < 4; ++i) {
        #pragma unroll
        for (int j = 0; j < 4; ++j) {
            int col = col0 + j * 16;
            #pragma unroll
            for (int r = 0; r < 4; ++r) {
                long idx = (long)(row0 + i * 16 + r) * N + col;
                float u = accu[i][j][r];
                float v = accv[i][j][r];
                float sl = u / (1.0f + __expf(-u));
                C[idx] = (bf16)(sl * v);
            }
        }
    }
}

// ---------------- RoPE prep: qkv bf16 [4096,3072] -> Q [B,H,S,64], K [B,KH,S,64] ----------------
// NOTE: Q is prescaled by 1/sqrt(HD) = 0.125 here (exact power-of-2 in bf16),
// so attn_fwd uses raw QK^T scores.
__global__ __launch_bounds__(256)
void rope_prep(const bf16* __restrict__ qkv, const float* __restrict__ fr,
               bf16* __restrict__ Qo, bf16* __restrict__ Ko) {
    const int row = blockIdx.x;            // b*SEQ + s
    const int b = row >> 11, s = row & 2047;
    const int t = threadIdx.x;
    const long rbase = (long)row * QKVN;
    #pragma unroll
    for (int i = 0; i < 4; ++i) {          // 1024 q pairs
        int p = t + i * 256;
        int hh = p >> 5, d = p & 31;
        bf16x2 xv = *(const bf16x2*)(qkv + rbase + hh * 64 + 2 * d);
        float x0 = (float)xv[0], x1 = (float)xv[1];
        float2 cs = *(const float2*)(fr + (long)(s * 32 + d) * 2);
        bf16x2 o;
        o[0] = (bf16)((x0 * cs.x - x1 * cs.y) * 0.125f);
        o[1] = (bf16)((x1 * cs.x + x0 * cs.y) * 0.125f);
        *(bf16x2*)(Qo + ((long)(b * NH + hh) * SEQ + s) * HD + 2 * d) = o;
    }
    {                                       // 256 k pairs
        int kh = t >> 5, d = t & 31;
        bf16x2 xv = *(const bf16x2*)(qkv + rbase + EDIM + kh * 64 + 2 * d);
        float x0 = (float)xv[0], x1 = (float)xv[1];
        float2 cs = *(const float2*)(fr + (long)(s * 32 + d) * 2);
        bf16x2 o;
        o[0] = (bf16)(x0 * cs.x - x1 * cs.y);
        o[1] = (bf16)(x1 * cs.x + x0 * cs.y);
        *(bf16x2*)(Ko + ((long)(b * NKV + kh) * SEQ + s) * HD + 2 * d) = o;
    }
}

// ---------------- V prep: transpose into [B,KH,S/64,hd=64,kk=64] bf16 tiles ----------------
__global__ __launch_bounds__(256)
void v_prep(const bf16* __restrict__ qkv, bf16* __restrict__ Vt) {
    __shared__ bf16 tile[64 * 72];          // +8 pad to break transpose conflicts
    const int blk = blockIdx.x;             // b*256 + kvh*32 + st
    const int b = blk >> 8;
    const int kvh = (blk >> 5) & 7;
    const int st = blk & 31;
    const int t = threadIdx.x;
    #pragma unroll
    for (int i = 0; i < 2; ++i) {
        int c = t + i * 256;                // 512 chunks
        int kk = c >> 3, hdo = (c & 7) * 8;
        bf16x8 v = *(const bf16x8*)(qkv + (long)(b * SEQ + st * 64 + kk) * QKVN + 2560 + kvh * 64 + hdo);
        *(bf16x8*)(tile + kk * 72 + hdo) = v;
    }
    __syncthreads();
    const long obase = ((long)(b * NKV + kvh) * 32 + st) * 4096;
    #pragma unroll
    for (int i = 0; i < 2; ++i) {
        int c = t + i * 256;
        int hd = c >> 3, ko = (c & 7) * 8;
        bf16x8 v;
        #pragma unroll
        for (int j = 0; j < 8; ++j) v[j] = tile[(ko + j) * 72 + hd];
        *(bf16x8*)(Vt + obase + hd * 64 + ko) = v;
    }
}

// ---------------- flash attention (causal, GQA 4:1), swapped-QK^T ----------------
// 4 waves/block, each wave owns 32 q-rows independently (no block barriers).
// (256,3): attn's live set needs the ~170-reg budget; forcing 4 blocks/CU
// (128-reg cap) spills and regresses ~2x (R11). Identity qt order (LPT flip
// was neutral-to-negative, R13).
__global__ __launch_bounds__(256, 3)
void attn_fwd(const bf16* __restrict__ Q, const bf16* __restrict__ K,
              const bf16* __restrict__ Vt, bf16* __restrict__ Out) {
    __shared__ bf16 Ps[4][32][40];           // per-wave P, 40-elem stride (80B = 5x16B)
    const int tid = threadIdx.x, lane = tid & 63, w = tid >> 6;
    const int bh = blockIdx.x;               // batch*head (fast grid dim for balance)
    const int qt = blockIdx.y;               // 128-row q tile
    const int b = bh >> 5, h = bh & 31;
    const int kvh = h >> 2;
    const int ql = lane & 31;                // q-row owned by this lane
    const int hh = lane >> 5;                // lane half
    const int sw = (ql ^ (ql >> 3)) & 3;     // LDS 16B-block swizzle key
    const int q0 = qt * 128 + w * 32;        // wave's q base within seq
    const int qmax = q0 + 31;
    const long qbase  = ((long)(b * NH + h) * SEQ + q0) * HD;
    const long kvbase = ((long)(b * NKV + kvh) * SEQ) * HD;
    bf16* Pw = &Ps[w][0][0];

    bf16x8 qa[4];
    #pragma unroll
    for (int ds = 0; ds < 4; ++ds)
        qa[ds] = *(const bf16x8*)(Q + qbase + (long)ql * HD + ds * 16 + hh * 8);

    f32x16 oacc[2] = {};                     // O^T accumulators (2 d-tiles of 32)
    float mi = -1e30f, li = 0.f;

    const int nt64 = qt * 2 + 1 + (w >> 1);
    for (int kt = 0; kt < nt64; ++kt) {
        const bf16* Kt  = K  + kvbase + (long)kt * (64 * HD);
        const bf16* Vtt = Vt + kvbase + (long)kt * 4096;
        bf16x8 ka[2][4], va[2][2][2];
        #pragma unroll
        for (int h2 = 0; h2 < 2; ++h2)
            #pragma unroll
            for (int ds = 0; ds < 4; ++ds)
                ka[h2][ds] = *(const bf16x8*)(Kt + (h2 * 32 + ql) * HD + ds * 16 + hh * 8);
        #pragma unroll
        for (int h2 = 0; h2 < 2; ++h2)
            #pragma unroll
            for (int t = 0; t < 2; ++t)
                #pragma unroll
                for (int c = 0; c < 2; ++c)
                    va[h2][t][c] = *(const bf16x8*)(Vtt + (t * 32 + ql) * 64 + h2 * 32 + c * 16 + hh * 8);
        const bool lastt = (kt == nt64 - 1);
        #pragma unroll
        for (int h2 = 0; h2 < 2; ++h2) {
            if (h2 == 1 && kt * 64 + 32 > qmax) break;   // wave-uniform skip
            f32x16 s = {};
            #pragma unroll
            for (int ds = 0; ds < 4; ++ds)
                s = __builtin_amdgcn_mfma_f32_32x32x16_bf16(ka[h2][ds], qa[ds], s, 0, 0, 0);
            if (lastt) {
                #pragma unroll
                for (int r = 0; r < 16; ++r) {
                    int kk = kt * 64 + h2 * 32 + (r & 3) + 8 * (r >> 2) + 4 * hh;
                    if (kk > q0 + ql) s[r] = -1e30f;
                }
            }
            float tmax = s[0];
            #pragma unroll
            for (int r = 1; r < 16; ++r) tmax = fmaxf(tmax, s[r]);
            tmax = fmaxf(tmax, __shfl_xor(tmax, 32, 64));
            if (!__all(tmax <= mi)) {
                float mnew = fmaxf(mi, tmax);
                float alpha = __expf(mi - mnew);
                li *= alpha;
                #pragma unroll
                for (int r = 0; r < 16; ++r) { oacc[0][r] *= alpha; oacc[1][r] *= alpha; }
                mi = mnew;
            }
            float psum = 0.f;
            #pragma unroll
            for (int g2 = 0; g2 < 4; ++g2) {
                bf16x4 pw;
                #pragma unroll
                for (int j = 0; j < 4; ++j) {
                    float p = __expf(s[g2 * 4 + j] - mi);
                    psum += p;
                    pw[j] = (bf16)p;
                }
                *(bf16x4*)(Pw + ql * 40 + ((g2 ^ sw) << 3) + 4 * hh) = pw;
            }
            psum += __shfl_xor(psum, 32, 64);
            li += psum;
            bf16x8 p0 = *(const bf16x8*)(Pw + ql * 40 + ((hh ^ sw) << 3));
            bf16x8 p1 = *(const bf16x8*)(Pw + ql * 40 + (((2 + hh) ^ sw) << 3));
            #pragma unroll
            for (int t = 0; t < 2; ++t) {
                oacc[t] = __builtin_amdgcn_mfma_f32_32x32x16_bf16(va[h2][t][0], p0, oacc[t], 0, 0, 0);
                oacc[t] = __builtin_amdgcn_mfma_f32_32x32x16_bf16(va[h2][t][1], p1, oacc[t], 0, 0, 0);
            }
        }
    }

    float inv = 1.0f / li;
    const long obase = ((long)b * SEQ + q0 + ql) * EDIM + h * 64;
    #pragma unroll
    for (int t = 0; t < 2; ++t)
        #pragma unroll
        for (int rg = 0; rg < 4; ++rg) {
            bf16x4 o4;
            #pragma unroll
            for (int j = 0; j < 4; ++j) o4[j] = (bf16)(oacc[t][rg * 4 + j] * inv);
            *(bf16x4*)(Out + obase + t * 32 + rg * 8 + hh * 4) = o4;
        }
}

// ---------------- launcher ----------------
extern "C" void kernel_launch(void* const* d_in, const int* in_sizes, int n_in,
                              void* d_out, int out_size, void* d_ws, size_t ws_size,
                              hipStream_t stream) {
    const float* x    = (const float*)d_in[0];
    // d_in[1] = attention_mask (always causal tril; handled analytically)
    const float* fr   = (const float*)d_in[2];
    const float* wqkv = (const float*)d_in[3];
    const float* wo   = (const float*)d_in[4];
    const float* w1   = (const float*)d_in[5];
    const float* w2   = (const float*)d_in[6];
    const float* w3   = (const float*)d_in[7];
    const float* anw  = (const float*)d_in[8];
    const float* fnw  = (const float*)d_in[9];
    float* out = (float*)d_out;

    // ---- workspace budget (aliased layout), ~252 MiB ----
    const size_t SZ_WQKV = (size_t)QKVN * EDIM;     // 6291456
    const size_t SZ_WO   = (size_t)EDIM * EDIM;     // 4194304
    const size_t SZ_WFF  = (size_t)FF * EDIM;       // 16777216
    const size_t B_WQKV  = SZ_WQKV * 2;             // 12.6 MB
    const size_t B_WO    = SZ_WO * 2;               //  8.4 MB
    const size_t B_WFF   = SZ_WFF * 2;              // 33.6 MB
    const size_t B_HATTN = (size_t)NTOK * EDIM * 2; // 16.8 MB
    const size_t B_QKV   = (size_t)NTOK * QKVN * 2; // 25.2 MB
    const size_t B_SCR   = (size_t)NTOK * EDIM * 4; // 33.6 MB (h2 fp32; aliases Q/K/Vt)
    const size_t B_FF1   = (size_t)NTOK * FF * 2;   // 67.1 MB
    const size_t NEED = B_WQKV + B_WO + 3 * B_WFF + B_HATTN + B_QKV + B_SCR + B_FF1;
    if (ws_size < NEED) return;   // diagnostic: clean absmax-fail instead of GPU fault

    char* ws = (char*)d_ws;
    size_t off = 0;
    auto alloc = [&](size_t bytes) -> void* {
        void* p = ws + off;
        off += (bytes + 255) & ~(size_t)255;
        return p;
    };
    bf16* wqkv_b = (bf16*)alloc(B_WQKV);
    bf16* wo_b   = (bf16*)alloc(B_WO);
    bf16* w1_b   = (bf16*)alloc(B_WFF);
    bf16* w3_b   = (bf16*)alloc(B_WFF);
    bf16* w2_b   = (bf16*)alloc(B_WFF);
    bf16* h_attn = (bf16*)alloc(B_HATTN);           // h, then attn_out
    bf16* qkv_g  = (bf16*)alloc(B_QKV);             // qkv, then g
    char* scr    = (char*)alloc(B_SCR);             // Q/K/Vt region, then h2
    bf16* Qb  = (bf16*)scr;                                         // 16.8 MB
    bf16* Kb  = (bf16*)(scr + (size_t)BATCH * NH * SEQ * HD * 2);   //  4.2 MB
    bf16* Vtb = (bf16*)(scr + (size_t)BATCH * (NH + NKV) * SEQ * HD * 2); // 4.2 MB
    float* h2 = (float*)scr;                        // aliases Q/K/Vt (dead by then)
    bf16* ff1 = (bf16*)alloc(B_FF1);                // SwiGLU activation (single write)
    bf16* g_b = qkv_g;                              // reuse (qkv dead after preps)

    // 1. weights -> bf16 (2 fused launches, 2048-block grids for full BW occupancy)
    cvt3_f32_bf16<<<2048, 256, 0, stream>>>(w1, w1_b, w3, w3_b, w2, w2_b,
                                            (long)(SZ_WFF / 4));
    cvt2_f32_bf16<<<2048, 256, 0, stream>>>(wqkv, wqkv_b, (long)(SZ_WQKV / 4),
                                            wo, wo_b, (long)(SZ_WO / 4));
    // 2. h = rmsnorm(x) * attn_norm_w  (bf16)
    rmsnorm_bf16<<<NTOK, 256, 0, stream>>>(x, anw, h_attn);
    // 3. qkv = h @ w_qkv^T  (bf16 out)
    gemm_nt<1><<<dim3(QKVN / 128, NTOK / 128), 256, 0, stream>>>(
        h_attn, wqkv_b, qkv_g, nullptr, NTOK, QKVN, EDIM);
    // 4. RoPE + layout prep (Q prescaled by 0.125)
    rope_prep<<<NTOK, 256, 0, stream>>>(qkv_g, fr, Qb, Kb);
    v_prep<<<BATCH * NKV * (SEQ / 64), 256, 0, stream>>>(qkv_g, Vtb);
    // 5. attention -> attn_out (bf16, [4096,2048]); grid (bh, qt) for balance
    attn_fwd<<<dim3(BATCH * NH, SEQ / 128), 256, 0, stream>>>(Qb, Kb, Vtb, h_attn);
    // 6. h2 = x + attn_out @ w_o^T  (fp32; h2 aliases dead Q/K/Vt)
    gemm_nt<2><<<dim3(EDIM / 128, NTOK / 128), 256, 0, stream>>>(
        h_attn, wo_b, h2, x, NTOK, EDIM, EDIM);
    // 7. g = rmsnorm(h2) * ff_norm_w (bf16)
    rmsnorm_bf16<<<NTOK, 256, 0, stream>>>(h2, fnw, g_b);
    // 8. act = silu(g @ w1^T) * (g @ w3^T)  -- ONE fused kernel, in-register SwiGLU
    gemm_ff<<<dim3(FF / 128, NTOK / 128), 256, 0, stream>>>(
        g_b, w1_b, w3_b, ff1, NTOK, FF, EDIM);
    // 9. out = h2 + act @ w2^T  (fp32)
    gemm_nt<2><<<dim3(EDIM / 128, NTOK / 128), 256, 0, stream>>>(
        ff1, w2_b, out, h2, NTOK, EDIM, FF);
    (void)in_sizes; (void)n_in; (void)out_size; (void)ws_size;
}